// Round 1
// 508.666 us; speedup vs baseline: 1.0744x; 1.0744x over previous
//
#include <hip/hip_runtime.h>
#include <cstdint>
#include <cstddef>

typedef __attribute__((ext_vector_type(8))) short short8;
typedef __attribute__((ext_vector_type(4))) float f32x4;
typedef __attribute__((ext_vector_type(4))) short short4v;

__device__ __forceinline__ unsigned short f2bf(float f) {
  unsigned u = __builtin_bit_cast(unsigned, f);
  u += 0x7fffu + ((u >> 16) & 1u);   // round-to-nearest-even
  return (unsigned short)(u >> 16);
}

// Direct global->LDS DMA, 16 B per lane. LDS dest is wave-uniform base +
// lane*16 (linear!), so any swizzle must be applied on the GLOBAL source
// address and again on the LDS read side (both-sides-or-neither).
__device__ __forceinline__ void gload_lds16(const unsigned short* g, unsigned short* l) {
  __builtin_amdgcn_global_load_lds(
      (__attribute__((address_space(1))) unsigned int*)g,
      (__attribute__((address_space(3))) unsigned int*)l, 16, 0, 0);
}

// ---------------- kernel 0: fp32 -> bf16 weight conversion ----------------
__global__ __launch_bounds__(256) void cvt_k(const float* __restrict__ src,
                                             unsigned short* __restrict__ dst, int n) {
  int i = (blockIdx.x * 256 + threadIdx.x) * 4;
  if (i + 3 < n) {
    float4 v = *(const float4*)(src + i);
    short4v o;
    o.x = (short)f2bf(v.x); o.y = (short)f2bf(v.y);
    o.z = (short)f2bf(v.z); o.w = (short)f2bf(v.w);
    *(short4v*)(dst + i) = o;
  }
}

// ---------------- kernel 1: stage-1 GEMM + block-transpose write ----------
// Per k-block (kb=0..3): C1[b, q] = sum_p x[b, kb*1024+p] * w1[kb, q, p]
// Written transposed: Y[b*768 + (q/48)*192 + kb*48 + (q%48)]  (bf16)
// Tile: 64 rows x 192 cols, BK=64, 256 threads (2x2 wave grid).
// LDS: unpadded 64-short rows, XOR-swizzled 16B slots (slot ^ (row&7)).
// B tile staged via global_load_lds (pre-swizzled source); A tile (fp32->bf16
// convert) staged via VGPR with swizzled ds_write_b128.
__global__ __launch_bounds__(256, 4) void stage1_k(
    const float* __restrict__ x, const unsigned short* __restrict__ w1bf,
    unsigned short* __restrict__ Y) {
  __shared__ __attribute__((aligned(16))) unsigned short sh[(64 + 192) * 64]; // 8KB + 24KB
  unsigned short* As = sh;            // [64][64]
  unsigned short* Bs = sh + 64 * 64;  // [192][64]
  const int t  = threadIdx.x;
  const int r0 = blockIdx.x * 64;
  const int kb = blockIdx.y;

  const int lane = t & 63;
  const int w  = t >> 6;
  const int wm = w & 1, wn = w >> 1;
  const int lm = lane & 15;   // m (A) / n (B) / col (C)
  const int lk = lane >> 4;   // k-group 0..3

  f32x4 acc[2][6];
#pragma unroll
  for (int i = 0; i < 2; ++i)
#pragma unroll
    for (int j = 0; j < 6; ++j) acc[i][j] = (f32x4)0.0f;

  const float* xbase = x + (size_t)r0 * 4096 + kb * 1024;
  const unsigned short* wb = w1bf + (size_t)kb * 192 * 1024;
  const int ldsbase = (t & ~63) << 3;   // wave-uniform chunk base (shorts)

  for (int kt = 0; kt < 16; ++kt) {
    const int k0 = kt * 64;
    // ---- B tile: 192x64 bf16 via global_load_lds, swizzled source ----
#pragma unroll
    for (int i = 0; i < 6; ++i) {
      int c = i * 256 + t;              // chunk id 0..1535 (16 B each)
      int row = c >> 3, slot = c & 7;
      gload_lds16(wb + (size_t)row * 1024 + k0 + ((slot ^ (row & 7)) << 3),
                  Bs + (i * 256 << 3) + ldsbase);
    }
    // ---- A tile: 64x64 fp32 -> bf16, swizzled ds_write_b128 ----
#pragma unroll
    for (int j = 0; j < 2; ++j) {
      int u = t + 256 * j;
      int row = u >> 3, c8 = u & 7;
      const float* p = xbase + (size_t)row * 4096 + k0 + c8 * 8;
      float4 a0 = *(const float4*)p;
      float4 a1 = *(const float4*)(p + 4);
      short8 o;
      o[0] = (short)f2bf(a0.x); o[1] = (short)f2bf(a0.y);
      o[2] = (short)f2bf(a0.z); o[3] = (short)f2bf(a0.w);
      o[4] = (short)f2bf(a1.x); o[5] = (short)f2bf(a1.y);
      o[6] = (short)f2bf(a1.z); o[7] = (short)f2bf(a1.w);
      *(short8*)&As[(row << 6) + ((c8 ^ (row & 7)) << 3)] = o;
    }
    __syncthreads();   // drains vmcnt (DMA + x loads) and lgkmcnt
    // ---- MFMA: 2 k-steps of 32 ----
#pragma unroll
    for (int ks = 0; ks < 2; ++ks) {
      const int sl = ks * 4 + lk;       // 16B slot 0..7
      short8 a[2], b[6];
#pragma unroll
      for (int rt = 0; rt < 2; ++rt) {
        int r = wm * 32 + rt * 16 + lm;
        a[rt] = *(const short8*)&As[(r << 6) + ((sl ^ (r & 7)) << 3)];
      }
#pragma unroll
      for (int ct = 0; ct < 6; ++ct) {
        int r = wn * 96 + ct * 16 + lm;
        b[ct] = *(const short8*)&Bs[(r << 6) + ((sl ^ (r & 7)) << 3)];
      }
#pragma unroll
      for (int rt = 0; rt < 2; ++rt)
#pragma unroll
        for (int ct = 0; ct < 6; ++ct)
          acc[rt][ct] = __builtin_amdgcn_mfma_f32_16x16x32_bf16(a[rt], b[ct], acc[rt][ct], 0, 0, 0);
    }
    __syncthreads();
  }

  // ---- epilogue: transposed bf16 write to Y ----
#pragma unroll
  for (int rt = 0; rt < 2; ++rt) {
#pragma unroll
    for (int ct = 0; ct < 6; ++ct) {
      int q  = wn * 96 + ct * 16 + lm;          // 0..191
      int li = q / 48, j = q - li * 48;
      size_t base = (size_t)(r0 + wm * 32 + rt * 16 + lk * 4) * 768 + li * 192 + kb * 48 + j;
#pragma unroll
      for (int reg = 0; reg < 4; ++reg)
        Y[base + (size_t)reg * 768] = f2bf(acc[rt][ct][reg]);
    }
  }
}

// ---------------- kernel 2: stage-2 GEMM + bias ---------------------------
// Per l (0..3): out[b, l*1024+s] = sum_r Y[b, l, r] * w2[l, s, r] + bias
// Tile: 128x128, BK=64 (3 iters), 256 threads (2x2 waves). LDS 32 KB ->
// 4 blocks/CU. Both tiles staged via global_load_lds (swizzled source).
// Grid flattened to 4096 with bijective XCD-chunked decode so the 8 n0-blocks
// sharing the same Y rows land on one XCD (Y slice per XCD ~3.1 MB <= 4 MB L2).
__global__ __launch_bounds__(256, 4) void stage2_k(
    const unsigned short* __restrict__ Y, const unsigned short* __restrict__ w2bf,
    const float* __restrict__ bias, float* __restrict__ out) {
  __shared__ __attribute__((aligned(16))) unsigned short sh[2 * 128 * 64]; // 32 KB
  unsigned short* As = sh;             // [128][64] Y tile
  unsigned short* Bs = sh + 128 * 64;  // [128][64] w2 tile

  // XCD-chunked bijective remap (nwg = 4096, divisible by 8)
  int lin  = blockIdx.x;                        // 0..4095, xcd = lin & 7
  int virt = ((lin & 7) << 9) + (lin >> 3);     // contiguous 512-block chunk per XCD
  const int n0 = (virt & 7) * 128;
  const int r0 = ((virt >> 3) & 127) * 128;
  const int l  = virt >> 10;

  const int t = threadIdx.x;
  const int lane = t & 63;
  const int w  = t >> 6;
  const int wm = w & 1, wn = w >> 1;
  const int lm = lane & 15;
  const int lk = lane >> 4;

  f32x4 acc[4][4];
#pragma unroll
  for (int i = 0; i < 4; ++i)
#pragma unroll
    for (int j = 0; j < 4; ++j) acc[i][j] = (f32x4)0.0f;

  const unsigned short* ybase = Y + (size_t)r0 * 768 + l * 192;
  const unsigned short* wbase = w2bf + (size_t)(l * 1024 + n0) * 192;
  const int ldsbase = (t & ~63) << 3;   // wave-uniform chunk base (shorts)

  for (int kt = 0; kt < 3; ++kt) {
    const int k0 = kt * 64;
#pragma unroll
    for (int i = 0; i < 4; ++i) {
      int c = i * 256 + t;              // chunk 0..1023
      int row = c >> 3, slot = c & 7;
      int sc = k0 + ((slot ^ (row & 7)) << 3);
      gload_lds16(ybase + (size_t)row * 768 + sc, As + (i * 256 << 3) + ldsbase);
      gload_lds16(wbase + (size_t)row * 192 + sc, Bs + (i * 256 << 3) + ldsbase);
    }
    __syncthreads();
#pragma unroll
    for (int ks = 0; ks < 2; ++ks) {
      const int sl = ks * 4 + lk;
      short8 a[4], b[4];
#pragma unroll
      for (int rt = 0; rt < 4; ++rt) {
        int r = wm * 64 + rt * 16 + lm;
        a[rt] = *(const short8*)&As[(r << 6) + ((sl ^ (r & 7)) << 3)];
      }
#pragma unroll
      for (int ct = 0; ct < 4; ++ct) {
        int r = wn * 64 + ct * 16 + lm;
        b[ct] = *(const short8*)&Bs[(r << 6) + ((sl ^ (r & 7)) << 3)];
      }
#pragma unroll
      for (int rt = 0; rt < 4; ++rt)
#pragma unroll
        for (int ct = 0; ct < 4; ++ct)
          acc[rt][ct] = __builtin_amdgcn_mfma_f32_16x16x32_bf16(a[rt], b[ct], acc[rt][ct], 0, 0, 0);
    }
    __syncthreads();
  }

  // ---- epilogue: bias + per-wave LDS transpose, coalesced float4 stores ----
  // All LDS reads done after final barrier; each wave reuses a private
  // 16x(64+4 pad) float slice (4352 B x 4 waves = 17.4 KB <= 32 KB).
  float* LF = (float*)sh + w * 1088;
  float bv[4];
#pragma unroll
  for (int ct = 0; ct < 4; ++ct)
    bv[ct] = bias[l * 1024 + n0 + wn * 64 + ct * 16 + lm];

#pragma unroll
  for (int rt = 0; rt < 4; ++rt) {
#pragma unroll
    for (int ct = 0; ct < 4; ++ct)
#pragma unroll
      for (int reg = 0; reg < 4; ++reg)
        LF[(lk * 4 + reg) * 68 + ct * 16 + lm] = acc[rt][ct][reg] + bv[ct];
    // wave-local: compiler inserts lgkmcnt waits; no __syncthreads needed
#pragma unroll
    for (int it = 0; it < 4; ++it) {
      int idx = it * 64 + lane;     // 256 float4 chunks in 16x64 region
      int rr = idx >> 4, cc = idx & 15;
      float4 vv = *(const float4*)&LF[rr * 68 + cc * 4];
      *(float4*)&out[(size_t)(r0 + wm * 64 + rt * 16 + rr) * 4096 + l * 1024 + n0 + wn * 64 + cc * 4] = vv;
    }
  }
}

// ---------------- launch ---------------------------------------------------
extern "C" void kernel_launch(void* const* d_in, const int* in_sizes, int n_in,
                              void* d_out, int out_size, void* d_ws, size_t ws_size,
                              hipStream_t stream) {
  const float* x    = (const float*)d_in[0];
  const float* w1   = (const float*)d_in[1];
  const float* w2   = (const float*)d_in[2];
  const float* bias = (const float*)d_in[3];
  float* out = (float*)d_out;

  // workspace layout: Y (24 MB) | w1bf (1.5 MB) | w2bf (1.5 MB)
  unsigned short* Y    = (unsigned short*)d_ws;
  unsigned short* w1bf = (unsigned short*)((char*)d_ws + 25165824);
  unsigned short* w2bf = (unsigned short*)((char*)d_ws + 25165824 + 1572864);

  cvt_k<<<768, 256, 0, stream>>>(w1, w1bf, 786432);
  cvt_k<<<768, 256, 0, stream>>>(w2, w2bf, 786432);
  stage1_k<<<dim3(256, 4), 256, 0, stream>>>(x, w1bf, Y);
  stage2_k<<<4096, 256, 0, stream>>>(Y, w2bf, bias, out);
}